// Round 2
// baseline (1622.113 us; speedup 1.0000x reference)
//
#include <hip/hip_runtime.h>

// Problem: DirectInterpGNN — segment-sum over edges, per-vertex coef, per-edge gather.
// All f32. N_V=500000, N_E=16000000.
// ws layout: num[nv] | den[nv] | coef[nv] | a_cache[ne] (optional, if ws fits)

__global__ void zero_f32(float* __restrict__ p, int n) {
    int i = blockIdx.x * blockDim.x + threadIdx.x;
    int stride = gridDim.x * blockDim.x;
    for (; i < n; i += stride) p[i] = 0.0f;
}

__global__ void accum(const float* __restrict__ edge_attr,
                      const int* __restrict__ src,
                      float* __restrict__ num,
                      float* __restrict__ den,
                      float* __restrict__ a_cache,
                      int ne4, int n_edges) {
    int t = blockIdx.x * blockDim.x + threadIdx.x;
    int stride = gridDim.x * blockDim.x;
    for (int i = t; i < ne4; i += stride) {
        const float4* ea = reinterpret_cast<const float4*>(edge_attr + 12ll * i);
        float4 w0 = ea[0], w1 = ea[1], w2 = ea[2];
        int4 s = reinterpret_cast<const int4*>(src)[i];
        // edge layout across the three float4s: (A0 S0 v0 A1)(S1 v1 A2 S2)(v2 A3 S3 v3)
        float A0 = w0.x, d0 = w0.x * w0.y * w0.z;
        float A1 = w0.w, d1 = w0.w * w1.x * w1.y;
        float A2 = w1.z, d2 = w1.z * w1.w * w2.x;
        float A3 = w2.y, d3 = w2.y * w2.z * w2.w;
        atomicAdd(&num[s.x], A0); atomicAdd(&den[s.x], d0);
        atomicAdd(&num[s.y], A1); atomicAdd(&den[s.y], d1);
        atomicAdd(&num[s.z], A2); atomicAdd(&den[s.z], d2);
        atomicAdd(&num[s.w], A3); atomicAdd(&den[s.w], d3);
        if (a_cache) reinterpret_cast<float4*>(a_cache)[i] = make_float4(A0, A1, A2, A3);
    }
    // scalar tail (n_edges % 4)
    for (int e = 4 * ne4 + t; e < n_edges; e += stride) {
        float A = edge_attr[3ll * e];
        float S = edge_attr[3ll * e + 1];
        float v = edge_attr[3ll * e + 2];
        int s = src[e];
        atomicAdd(&num[s], A);
        atomicAdd(&den[s], A * S * v);
        if (a_cache) a_cache[e] = A;
    }
}

__global__ void coef_k(const float* __restrict__ vattr,
                       const float* __restrict__ num,
                       const float* __restrict__ den,
                       float* __restrict__ coef, int nv) {
    int v = blockIdx.x * blockDim.x + threadIdx.x;
    int stride = gridDim.x * blockDim.x;
    for (; v < nv; v += stride) {
        float2 va = reinterpret_cast<const float2*>(vattr)[v];  // (A_ii, C_i)
        float gam = num[v] / den[v];          // NaN for isolated vertices; never gathered
        coef[v] = (1.0f - va.y) * (-gam / va.x);
    }
}

__global__ void finalize(const float* __restrict__ a_cache,
                         const float* __restrict__ edge_attr,
                         const int* __restrict__ src,
                         const float* __restrict__ coef,
                         float* __restrict__ out, int ne4, int n_edges) {
    int t = blockIdx.x * blockDim.x + threadIdx.x;
    int stride = gridDim.x * blockDim.x;
    for (int i = t; i < ne4; i += stride) {
        int4 s = reinterpret_cast<const int4*>(src)[i];
        float4 A;
        if (a_cache) {
            A = reinterpret_cast<const float4*>(a_cache)[i];
        } else {
            const float* e = edge_attr + 12ll * i;
            A.x = e[0]; A.y = e[3]; A.z = e[6]; A.w = e[9];
        }
        float4 w;
        w.x = coef[s.x] * A.x;
        w.y = coef[s.y] * A.y;
        w.z = coef[s.z] * A.z;
        w.w = coef[s.w] * A.w;
        reinterpret_cast<float4*>(out)[i] = w;
    }
    for (int e = 4 * ne4 + t; e < n_edges; e += stride) {
        float A = a_cache ? a_cache[e] : edge_attr[3ll * e];
        out[e] = coef[src[e]] * A;
    }
}

extern "C" void kernel_launch(void* const* d_in, const int* in_sizes, int n_in,
                              void* d_out, int out_size, void* d_ws, size_t ws_size,
                              hipStream_t stream) {
    const float* vattr = (const float*)d_in[0];   // (nv, 2)
    const float* eattr = (const float*)d_in[1];   // (ne, 3)
    const int*   pair  = (const int*)d_in[2];     // (2, ne)
    int nv = in_sizes[0] / 2;
    int ne = in_sizes[1] / 3;
    const int* src = pair;                         // row 0
    float* out = (float*)d_out;

    float* num  = (float*)d_ws;
    float* den  = num + nv;
    float* coef = den + nv;
    size_t base_bytes = (size_t)3 * nv * sizeof(float);
    float* a_cache = nullptr;
    if (ws_size >= base_bytes + (size_t)ne * sizeof(float))
        a_cache = coef + nv;

    int ne4 = ne / 4;
    const int B = 256;
    auto capped = [](long long want, int cap) {
        return (int)(want < cap ? (want > 1 ? want : 1) : cap);
    };
    int zgrid = capped((2LL * nv + B - 1) / B, 2048);
    int agrid = capped(((long long)ne4 + B - 1) / B, 4096);
    int cgrid = capped(((long long)nv + B - 1) / B, 2048);

    zero_f32<<<zgrid, B, 0, stream>>>(num, 2 * nv);
    accum<<<agrid, B, 0, stream>>>(eattr, src, num, den, a_cache, ne4, ne);
    coef_k<<<cgrid, B, 0, stream>>>(vattr, num, den, coef, nv);
    finalize<<<agrid, B, 0, stream>>>(a_cache, eattr, src, coef, out, ne4, ne);
}